// Round 11
// baseline (190.167 us; speedup 1.0000x reference)
//
#include <hip/hip_runtime.h>

#define N_NODES 2048
#define N_EDGES 65536
#define NV 6
#define C 32
#define BLK 256

// ---------------------------------------------------------------------------
// ws layout (floats): cnt[2048] | sum1|sum2|sum3 [65536 each] | h1|h2|h3.
// memset zeroes only cnt+sum1 (270 KB); sum2/sum3 zeroed inside edge1.
// R9 lesson: L2-resident atomic scatter BEATS dense msg round-trip.
// R10 lesson: e23 is latency-bound at 2 waves/SIMD (~45% VALU eff).
// ---------------------------------------------------------------------------

// Layer 1 (in_c = 1), wave per 32 edges. ea (192 floats) + x[src] (32) staged
// in LDS per wave (same-wave write -> broadcast read, proven pattern).
// W1 row in 6 regs/lane. Grid 512: 131072 threads == 2*N*C exactly, so the
// sum2/sum3 zeroing is one element per thread.
__global__ __launch_bounds__(BLK) void edge1_kernel(
    const float* __restrict__ x, const float* __restrict__ ea,
    const int* __restrict__ src, const int* __restrict__ dst,
    const float* __restrict__ W1, const float* __restrict__ b1,
    float* __restrict__ sum1, float* __restrict__ sum23,
    float* __restrict__ cnt) {
    __shared__ float ebuf[4][192];
    __shared__ float xbuf[4][32];
    const int tid = blockIdx.x * BLK + threadIdx.x;
    sum23[tid] = 0.0f;  // zero sum2+sum3 (exact cover)
    const int lane = threadIdx.x & 63;
    const int o = lane & 31;
    const int half = lane >> 5;
    const int w = threadIdx.x >> 6;
    const int e0 = (tid >> 6) * 32;

    float w1r[NV];
#pragma unroll
    for (int v = 0; v < NV; v++) w1r[v] = W1[v * C + o];
    const float b1o = b1[o];

    // stage 32 edges' attrs + x[src]
    if (lane < 48)
        *(float4*)&ebuf[w][lane * 4] = ((const float4*)(ea + (size_t)e0 * NV))[lane];
    if (lane < 32) xbuf[w][lane] = x[src[e0 + lane]];

#pragma unroll 4
    for (int k = 0; k < 16; k++) {
        const int e = half * 16 + k;              // half 0: 0..15, half 1: 16..31
        const float* ep = &ebuf[w][e * 6];        // broadcast reads
        float t = b1o;
        t = fmaf(ep[0], w1r[0], t);
        t = fmaf(ep[1], w1r[1], t);
        t = fmaf(ep[2], w1r[2], t);
        t = fmaf(ep[3], w1r[3], t);
        t = fmaf(ep[4], w1r[4], t);
        t = fmaf(ep[5], w1r[5], t);
        const float m = xbuf[w][e] * fmaxf(t, 0.0f);
        const int d = dst[e0 + e];                // broadcast, L1-hot
        atomicAdd(&sum1[d * C + o], m);
        if (o == 0) atomicAdd(&cnt[d], 1.0f);     // each edge counted once
    }
}

// Finalize a layer: h_out = relu(sum/max(cnt,1) + h_prev @ root + bias)
template <int IN_C>
__global__ void node_kernel(const float* __restrict__ sum,
                            const float* __restrict__ cnt,
                            const float* __restrict__ hprev,
                            const float* __restrict__ root,
                            const float* __restrict__ bias,
                            float* __restrict__ hout) {
    int t = blockIdx.x * blockDim.x + threadIdx.x;
    int n = t >> 5, o = t & 31;
    float inv = 1.0f / fmaxf(cnt[n], 1.0f);
    float acc = sum[t] * inv + bias[o];
#pragma unroll
    for (int i = 0; i < IN_C; i++) acc = fmaf(hprev[n * IN_C + i], root[i * C + o], acc);
    hout[t] = fmaxf(acc, 0.0f);
}

// Layers 2/3: reg-W core (R5/R10-proven math), register-dieted for
// 3 waves/SIMD (launch_bounds cap 170 VGPR). Grid 1024 -> 4096 waves,
// 2 eight-edge groups per wave, 1 group per grid-stride iteration.
// lane l: o=l&31, half=l>>5, i-slice [half*16,+16); wreg[16][6]+breg[16]
// = lane's exact j-loop footprint (112 VGPR). h staged per-wave in LDS
// (contiguous 1KB b128 write, broadcast b128 reads, 0 conflicts measured).
// dst loads hoisted next to src load to overlap latency.
__global__ __launch_bounds__(BLK, 3) void edge23_kernel(
    const float* __restrict__ hprev,   // [N, 32]
    const float* __restrict__ ea,      // [E, 6]
    const int* __restrict__ src,
    const int* __restrict__ dst,
    const float* __restrict__ W,       // [NV, 1024]
    const float* __restrict__ b,       // [1024]
    float* __restrict__ sumout)        // [N, 32]
{
    __shared__ float hb[4][256];
    const int lane = threadIdx.x & 63;
    const int o = lane & 31;
    const int half = lane >> 5;
    const int i0 = half * 16;
    const int w = threadIdx.x >> 6;
    float* hbw = &hb[w][0];

    float wreg[16][6], breg[16];
#pragma unroll
    for (int j = 0; j < 16; j++) {
#pragma unroll
        for (int v = 0; v < 6; v++) wreg[j][v] = W[v * 1024 + (i0 + j) * C + o];
        breg[j] = b[(i0 + j) * C + o];
    }

    const int nw = (gridDim.x * BLK) >> 6;               // 4096
    const int wid = (blockIdx.x * BLK + threadIdx.x) >> 6;
    for (int g = wid; g < N_EDGES / 8; g += nw) {
        const int e0 = g * 8;
        const int4 sq = *(const int4*)&src[e0 + half * 4];
        const int4 dA = *(const int4*)&dst[e0];           // hoisted
        const int4 dB = *(const int4*)&dst[e0 + 4];
        float4 hq;
        hq.x = hprev[sq.x * C + o];
        hq.y = hprev[sq.y * C + o];
        hq.z = hprev[sq.z * C + o];
        hq.w = hprev[sq.w * C + o];
        *(float4*)&hbw[half * 128 + o * 4] = hq;          // contiguous 1KB write

        float accs[8];
        const float4* eap4 = (const float4*)(ea + (size_t)e0 * NV);
#pragma unroll
        for (int sub = 0; sub < 2; sub++) {
            float eaf[24];
#pragma unroll
            for (int t = 0; t < 6; t++) *(float4*)&eaf[t * 4] = eap4[sub * 6 + t];
            float a0 = 0.0f, a1 = 0.0f, a2 = 0.0f, a3 = 0.0f;
#pragma unroll
            for (int j = 0; j < 16; j++) {
                const float4 hA = *(const float4*)&hbw[sub * 128 + (i0 + j) * 4];
                const float bb = breg[j];
                const float w0 = wreg[j][0], w1 = wreg[j][1], w2 = wreg[j][2];
                const float w3 = wreg[j][3], w4 = wreg[j][4], w5 = wreg[j][5];
                float t0 = bb, t1 = bb, t2 = bb, t3 = bb;
                t0 = fmaf(eaf[0],  w0, t0); t1 = fmaf(eaf[6],  w0, t1);
                t2 = fmaf(eaf[12], w0, t2); t3 = fmaf(eaf[18], w0, t3);
                t0 = fmaf(eaf[1],  w1, t0); t1 = fmaf(eaf[7],  w1, t1);
                t2 = fmaf(eaf[13], w1, t2); t3 = fmaf(eaf[19], w1, t3);
                t0 = fmaf(eaf[2],  w2, t0); t1 = fmaf(eaf[8],  w2, t1);
                t2 = fmaf(eaf[14], w2, t2); t3 = fmaf(eaf[20], w2, t3);
                t0 = fmaf(eaf[3],  w3, t0); t1 = fmaf(eaf[9],  w3, t1);
                t2 = fmaf(eaf[15], w3, t2); t3 = fmaf(eaf[21], w3, t3);
                t0 = fmaf(eaf[4],  w4, t0); t1 = fmaf(eaf[10], w4, t1);
                t2 = fmaf(eaf[16], w4, t2); t3 = fmaf(eaf[22], w4, t3);
                t0 = fmaf(eaf[5],  w5, t0); t1 = fmaf(eaf[11], w5, t1);
                t2 = fmaf(eaf[17], w5, t2); t3 = fmaf(eaf[23], w5, t3);
                a0 = fmaf(hA.x, fmaxf(t0, 0.0f), a0);
                a1 = fmaf(hA.y, fmaxf(t1, 0.0f), a1);
                a2 = fmaf(hA.z, fmaxf(t2, 0.0f), a2);
                a3 = fmaf(hA.w, fmaxf(t3, 0.0f), a3);
            }
            accs[sub * 4 + 0] = a0; accs[sub * 4 + 1] = a1;
            accs[sub * 4 + 2] = a2; accs[sub * 4 + 3] = a3;
        }
#pragma unroll
        for (int k = 0; k < 8; k++) accs[k] += __shfl_down(accs[k], 32);
        if (lane < 32) {
            atomicAdd(&sumout[dA.x * C + o], accs[0]);
            atomicAdd(&sumout[dA.y * C + o], accs[1]);
            atomicAdd(&sumout[dA.z * C + o], accs[2]);
            atomicAdd(&sumout[dA.w * C + o], accs[3]);
            atomicAdd(&sumout[dB.x * C + o], accs[4]);
            atomicAdd(&sumout[dB.y * C + o], accs[5]);
            atomicAdd(&sumout[dB.z * C + o], accs[6]);
            atomicAdd(&sumout[dB.w * C + o], accs[7]);
        }
    }
}

// CBT: out[i,j] = sum_k |h[i,k]-h[j,k]|. 256-thread blocks, 64x64 tiles.
__global__ __launch_bounds__(BLK) void cbt_kernel(const float* __restrict__ h,
                                                  float* __restrict__ out) {
    __shared__ float hj_s[64][33];
    __shared__ float hi_s[64 * 32];
    const int lane = threadIdx.x & 63;
    const int w = threadIdx.x >> 6;
    const int j0 = blockIdx.x * 64;
    const int i0 = blockIdx.y * 64;
    for (int t = threadIdx.x; t < 64 * 32; t += BLK) {
        hj_s[t >> 5][t & 31] = h[j0 * 32 + t];
        hi_s[t] = h[i0 * 32 + t];
    }
    __syncthreads();
    float hj[32];
#pragma unroll
    for (int k = 0; k < 32; k++) hj[k] = hj_s[lane][k];
    const int j = j0 + lane;
#pragma unroll 4
    for (int ii = w * 16; ii < w * 16 + 16; ii++) {
        float acc = 0.0f;
#pragma unroll
        for (int k = 0; k < 32; k++) acc += fabsf(hi_s[ii * 32 + k] - hj[k]);
        out[(size_t)(i0 + ii) * N_NODES + j] = acc;
    }
}

extern "C" void kernel_launch(void* const* d_in, const int* in_sizes, int n_in,
                              void* d_out, int out_size, void* d_ws, size_t ws_size,
                              hipStream_t stream) {
    const float* x         = (const float*)d_in[0];
    const float* edge_attr = (const float*)d_in[1];
    const int*   edge_idx  = (const int*)d_in[2];
    const float* W1 = (const float*)d_in[3];
    const float* b1 = (const float*)d_in[4];
    const float* root1 = (const float*)d_in[5];
    const float* bias1 = (const float*)d_in[6];
    const float* W2 = (const float*)d_in[7];
    const float* b2 = (const float*)d_in[8];
    const float* root2 = (const float*)d_in[9];
    const float* bias2 = (const float*)d_in[10];
    const float* W3 = (const float*)d_in[11];
    const float* b3 = (const float*)d_in[12];
    const float* root3 = (const float*)d_in[13];
    const float* bias3 = (const float*)d_in[14];

    const int* src = edge_idx;            // row 0
    const int* dst = edge_idx + N_EDGES;  // row 1

    float* ws   = (float*)d_ws;
    float* cnt  = ws;
    float* sum1 = ws + N_NODES;
    float* sum2 = sum1 + N_NODES * C;
    float* sum3 = sum2 + N_NODES * C;
    float* h1   = sum3 + N_NODES * C;
    float* h2   = h1 + N_NODES * C;
    float* h3   = h2 + N_NODES * C;

    // zero cnt + sum1 only (270 KB); sum2/sum3 zeroed inside edge1
    hipMemsetAsync(d_ws, 0, (size_t)(N_NODES + N_NODES * C) * sizeof(float), stream);

    // Layer 1 (wave-per-32-edges; degree count + sum2/3 zeroing fused)
    edge1_kernel<<<512, BLK, 0, stream>>>(x, edge_attr, src, dst, W1, b1,
                                          sum1, sum2, cnt);
    node_kernel<1><<<(N_NODES * C) / BLK, BLK, 0, stream>>>(sum1, cnt, x, root1, bias1, h1);

    // Layer 2
    edge23_kernel<<<1024, BLK, 0, stream>>>(h1, edge_attr, src, dst, W2, b2, sum2);
    node_kernel<C><<<(N_NODES * C) / BLK, BLK, 0, stream>>>(sum2, cnt, h1, root2, bias2, h2);

    // Layer 3
    edge23_kernel<<<1024, BLK, 0, stream>>>(h2, edge_attr, src, dst, W3, b3, sum3);
    node_kernel<C><<<(N_NODES * C) / BLK, BLK, 0, stream>>>(sum3, cnt, h2, root3, bias3, h3);

    // CBT
    cbt_kernel<<<dim3(N_NODES / 64, N_NODES / 64), BLK, 0, stream>>>(h3, (float*)d_out);
}